// Round 1
// baseline (728.580 us; speedup 1.0000x reference)
//
#include <hip/hip_runtime.h>
#include <hip/hip_bf16.h>

#define N_NODES  10000
#define NPAD     10048      // 157*64, padded j-range
#define FIN      256
#define D        64
#define NTILE    157        // ceil(10000/64)
#define ROWTILES 625        // 10000/16
#define NSPLIT   8
#define ALPHA    0.2f

typedef __attribute__((ext_vector_type(8))) short bf16x8;
typedef __attribute__((ext_vector_type(4))) float f32x4;
typedef __attribute__((ext_vector_type(4))) int   i32x4;

__device__ __forceinline__ short bf16bits(float x) {
  union { __hip_bfloat16 b; short s; } u;
  u.b = __float2bfloat16(x);
  return u.s;
}
__device__ __forceinline__ unsigned flipf(float x) {
  unsigned u = __float_as_uint(x);
  return (u & 0x80000000u) ? ~u : (u | 0x80000000u);
}
__device__ __forceinline__ float unflipf(unsigned k) {
  return (k & 0x80000000u) ? __uint_as_float(k ^ 0x80000000u)
                           : __uint_as_float(~k);
}

// k1: one wave per row i. Computes Wh[i][lane] (f32), writes bf16 transposed
// WhT[lane][i], f1[i], f2[i], and atomicMax of flipped f2 -> f2max.
// Rows in [N_NODES, NPAD) just zero the WhT pad columns.
__global__ __launch_bounds__(256) void k1_proj(
    const float* __restrict__ h, const float* __restrict__ W,
    const float* __restrict__ a,
    float* __restrict__ f1, float* __restrict__ f2,
    unsigned* __restrict__ f2maxW, short* __restrict__ whT) {
  int wid  = (blockIdx.x << 2) + (threadIdx.x >> 6);
  int lane = threadIdx.x & 63;
  if (wid >= NPAD) return;
  if (wid >= N_NODES) {               // zero the j-pad of WhT
    whT[(size_t)lane * NPAD + wid] = 0;
    return;
  }
  const float* hrow = h + (size_t)wid * FIN;
  float acc = 0.f;
#pragma unroll 4
  for (int k = 0; k < FIN; k += 4) {
    float4 hv = *(const float4*)(hrow + k);
    acc += hv.x * W[(k + 0) * D + lane];
    acc += hv.y * W[(k + 1) * D + lane];
    acc += hv.z * W[(k + 2) * D + lane];
    acc += hv.w * W[(k + 3) * D + lane];
  }
  whT[(size_t)lane * NPAD + wid] = bf16bits(acc);
  float p1 = acc * a[lane];
  float p2 = acc * a[D + lane];
#pragma unroll
  for (int off = 32; off; off >>= 1) {
    p1 += __shfl_xor(p1, off);
    p2 += __shfl_xor(p2, off);
  }
  if (lane == 0) {
    f1[wid] = p1;
    f2[wid] = p2;
    atomicMax(f2maxW, flipf(p2));
  }
}

// k2: wave handles 16 rows x 64 dims over 1/NSPLIT of the j range.
// A (P tile) built in-register from adj + f2; B loaded straight from global
// bf16 WhT (L2-resident). Partial acc / s combined via atomicAdd.
__global__ __launch_bounds__(256) void k2_attn(
    const int* __restrict__ adj, const float* __restrict__ f1,
    const float* __restrict__ f2, const unsigned* __restrict__ f2maxW,
    const short* __restrict__ whT,
    float* __restrict__ accW, float* __restrict__ sW) {
  int wg = (blockIdx.x << 2) + (threadIdx.x >> 6);
  if (wg >= ROWTILES * NSPLIT) return;
  int lane    = threadIdx.x & 63;
  int rowtile = wg % ROWTILES;
  int split   = wg / ROWTILES;
  int r = lane & 15;      // A row offset within tile; also C col offset
  int g = lane >> 4;      // k-group
  int row = rowtile * 16 + r;

  float f1r  = f1[row];
  float f2m  = unflipf(*f2maxW);
  float mraw = f1r + f2m;
  float Mhat = fmaxf(mraw, ALPHA * mraw);   // leaky(f1r + f2max) >= all e_ij

  f32x4 acc[4];
#pragma unroll
  for (int cb = 0; cb < 4; ++cb) acc[cb] = (f32x4){0.f, 0.f, 0.f, 0.f};
  float s_part = 0.f;

  const int* adjrow = adj + (size_t)row * N_NODES;

  for (int t = split; t < NTILE; t += NSPLIT) {
    int j0 = t << 6;
    bf16x8 afrag[2];
#pragma unroll
    for (int ks = 0; ks < 2; ++ks) {
      int  jc  = j0 + ks * 32 + g * 8;
      bool inb = (jc < N_NODES);                    // chunks are 8-aligned, N%8==0
      int  jcl = inb ? jc : (N_NODES - 8);          // clamped, always in-bounds
      i32x4 a0 = *(const i32x4*)(adjrow + jcl);
      i32x4 a1 = *(const i32x4*)(adjrow + jcl + 4);
      f32x4 F0 = *(const f32x4*)(f2 + jcl);
      f32x4 F1 = *(const f32x4*)(f2 + jcl + 4);
      float p[8];
#pragma unroll
      for (int e = 0; e < 4; ++e) {
        float e0 = f1r + F0[e];
        e0 = fmaxf(e0, ALPHA * e0);
        float pv0 = __expf(e0 - Mhat);
        p[e] = (inb && a0[e] != 0) ? pv0 : 0.f;
        float e1 = f1r + F1[e];
        e1 = fmaxf(e1, ALPHA * e1);
        float pv1 = __expf(e1 - Mhat);
        p[4 + e] = (inb && a1[e] != 0) ? pv1 : 0.f;
      }
#pragma unroll
      for (int e = 0; e < 8; ++e) s_part += p[e];
#pragma unroll
      for (int e = 0; e < 8; ++e) afrag[ks][e] = bf16bits(p[e]);
    }
#pragma unroll
    for (int ks = 0; ks < 2; ++ks) {
      const short* bbase = whT + (size_t)r * NPAD + j0 + ks * 32 + g * 8;
#pragma unroll
      for (int cb = 0; cb < 4; ++cb) {
        bf16x8 bfrag = *(const bf16x8*)(bbase + (size_t)cb * 16 * NPAD);
        acc[cb] = __builtin_amdgcn_mfma_f32_16x16x32_bf16(afrag[ks], bfrag,
                                                          acc[cb], 0, 0, 0);
      }
    }
  }

  // denominator: reduce across the 4 k-groups (lanes r, r+16, r+32, r+48)
  s_part += __shfl_xor(s_part, 16);
  s_part += __shfl_xor(s_part, 32);

  int i0 = rowtile * 16;
#pragma unroll
  for (int cb = 0; cb < 4; ++cb)
#pragma unroll
    for (int q = 0; q < 4; ++q)
      atomicAdd(&accW[(size_t)(i0 + g * 4 + q) * D + cb * 16 + r], acc[cb][q]);
  if (lane < 16) atomicAdd(&sW[i0 + r], s_part);
}

// k3: out = ELU(acc / s)
__global__ __launch_bounds__(256) void k3_final(
    const float* __restrict__ accW, const float* __restrict__ sW,
    float* __restrict__ out) {
  int idx = blockIdx.x * 256 + threadIdx.x;
  if (idx >= N_NODES * D) return;
  float sv = fmaxf(sW[idx >> 6], 1e-30f);
  float v  = accW[idx] / sv;
  out[idx] = v > 0.f ? v : (__expf(v) - 1.f);
}

extern "C" void kernel_launch(void* const* d_in, const int* in_sizes, int n_in,
                              void* d_out, int out_size, void* d_ws, size_t ws_size,
                              hipStream_t stream) {
  const float* h   = (const float*)d_in[0];
  const int*   adj = (const int*)d_in[1];
  const float* W   = (const float*)d_in[2];
  const float* a   = (const float*)d_in[3];
  float* out = (float*)d_out;

  float* wsf = (float*)d_ws;
  // ws layout (floats): acc[640000] | s[10048] | f2max(+pad)[16] | f1[10048] | f2[10048] | whT(bf16 64*NPAD)
  float*    accW   = wsf;
  float*    sW     = wsf + 640000;
  unsigned* f2maxW = (unsigned*)(wsf + 650048);
  float*    f1W    = wsf + 650064;
  float*    f2W    = wsf + 660112;
  short*    whT    = (short*)(wsf + 670160);

  // zero acc + s + f2max in one memset
  hipMemsetAsync(accW, 0, (size_t)650064 * sizeof(float), stream);

  hipLaunchKernelGGL(k1_proj, dim3(NPAD / 4), dim3(256), 0, stream,
                     h, W, a, f1W, f2W, f2maxW, whT);
  hipLaunchKernelGGL(k2_attn, dim3(ROWTILES * NSPLIT / 4), dim3(256), 0, stream,
                     adj, f1W, f2W, f2maxW, whT, accW, sW);
  hipLaunchKernelGGL(k3_final, dim3((N_NODES * D + 255) / 256), dim3(256), 0, stream,
                     accW, sW, out);
}

// Round 2
// 638.372 us; speedup vs baseline: 1.1413x; 1.1413x over previous
//
#include <hip/hip_runtime.h>
#include <hip/hip_bf16.h>

#define N_NODES  10000
#define NPAD     10240      // 40*256 padded j-range
#define FIN      256
#define D        64
#define NT256    40         // j-tiles of 256
#define ROWTILES 625        // 10000/16
#define NSPLIT   4
#define ALPHA    0.2f

typedef __attribute__((ext_vector_type(8))) short bf16x8;
typedef __attribute__((ext_vector_type(4))) float f32x4;
typedef __attribute__((ext_vector_type(4))) int   i32x4;

__device__ __forceinline__ unsigned bf16bits(float x) {
  union { __hip_bfloat16 b; unsigned short s; } u;
  u.b = __float2bfloat16(x);
  return (unsigned)u.s;
}

// ---- k1: Wh = h@W, one wave per row; writes bf16 whT[d][j], f1, f2 ----------
__global__ __launch_bounds__(256) void k1_proj(
    const float* __restrict__ h, const float* __restrict__ W,
    const float* __restrict__ a,
    float* __restrict__ f1, float* __restrict__ f2,
    short* __restrict__ whT) {
  int wid  = (blockIdx.x << 2) + (threadIdx.x >> 6);
  int lane = threadIdx.x & 63;
  if (wid >= N_NODES) {                 // zero the j-pad columns of whT
    if (wid < NPAD) whT[(size_t)lane * NPAD + wid] = 0;
    return;
  }
  const float* hrow = h + (size_t)wid * FIN;
  float s0 = 0.f, s1 = 0.f, s2 = 0.f, s3 = 0.f;
#pragma unroll 4
  for (int k = 0; k < FIN; k += 4) {
    float4 hv = *(const float4*)(hrow + k);
    s0 += hv.x * W[(k + 0) * D + lane];
    s1 += hv.y * W[(k + 1) * D + lane];
    s2 += hv.z * W[(k + 2) * D + lane];
    s3 += hv.w * W[(k + 3) * D + lane];
  }
  float acc = (s0 + s1) + (s2 + s3);
  whT[(size_t)lane * NPAD + wid] = (short)bf16bits(acc);
  float p1 = acc * a[lane];
  float p2 = acc * a[D + lane];
#pragma unroll
  for (int off = 32; off; off >>= 1) {
    p1 += __shfl_xor(p1, off);
    p2 += __shfl_xor(p2, off);
  }
  if (lane == 0) { f1[wid] = p1; f2[wid] = p2; }
}

// ---- k1b: single-block max over f2 (replaces 10K same-address atomics) -----
__global__ __launch_bounds__(256) void k1b_max(
    const float* __restrict__ f2, float* __restrict__ f2maxF) {
  float m = -3.4e38f;
  for (int i = threadIdx.x; i < N_NODES; i += 256) m = fmaxf(m, f2[i]);
#pragma unroll
  for (int off = 32; off; off >>= 1) m = fmaxf(m, __shfl_xor(m, off));
  __shared__ float wm[4];
  if ((threadIdx.x & 63) == 0) wm[threadIdx.x >> 6] = m;
  __syncthreads();
  if (threadIdx.x == 0)
    *f2maxF = fmaxf(fmaxf(wm[0], wm[1]), fmaxf(wm[2], wm[3]));
}

// ---- k2: block = 16 rows x 256 cols tile; producer(coalesced adj -> P in
//      swizzled LDS) / consumer(MFMA, B from L2-resident whT). No atomics. ----
__global__ __launch_bounds__(256) void k2_attn(
    const int* __restrict__ adj, const float* __restrict__ f1,
    const float* __restrict__ f2, const float* __restrict__ f2maxF,
    const short* __restrict__ whT,
    float* __restrict__ accP, float* __restrict__ sP) {
  __shared__ float ldsF[4096];          // 16 KB: P tile (8KB) then acc-reduce
  char* ldsB = (char*)ldsF;
  int tid = threadIdx.x;
  int rowtile = blockIdx.x % ROWTILES;
  int split   = blockIdx.x / ROWTILES;

  // producer mapping: thread t -> row t>>4, 4 cols at (t&15)*4 + sub*64
  int prow  = tid >> 4;
  int cbase = (tid & 15) * 4;
  int grow  = rowtile * 16 + prow;
  float f1r  = f1[grow];
  float mraw = f1r + *f2maxF;
  float Mhat = fmaxf(mraw, ALPHA * mraw);     // leaky(f1_i + max_j f2_j) >= all e_ij
  const int* adjrow = adj + (size_t)grow * N_NODES;

  // consumer mapping (MFMA fragment)
  int lane = tid & 63;
  int w    = tid >> 6;        // wave = j-subtile of 64
  int r2   = lane & 15;
  int g    = lane >> 4;

  f32x4 acc[4];
#pragma unroll
  for (int cb = 0; cb < 4; ++cb) acc[cb] = (f32x4){0.f, 0.f, 0.f, 0.f};
  float sth = 0.f;

  // precomputed swizzled LDS byte offsets (XOR bit4 with row&7)
  int pboff[4];
#pragma unroll
  for (int sub = 0; sub < 4; ++sub)
    pboff[sub] = (prow * 512 + (cbase + sub * 64) * 2) ^ ((prow & 7) << 4);
  int cboff[2];
#pragma unroll
  for (int ks = 0; ks < 2; ++ks)
    cboff[ks] = (r2 * 512 + (w * 64 + ks * 32 + g * 8) * 2) ^ ((r2 & 7) << 4);
  const short* bbase = whT + (size_t)r2 * NPAD + w * 64 + g * 8;

  for (int tt = split; tt < NT256; tt += NSPLIT) {
    int j0 = tt << 8;
    // ---- producer: coalesced adj + f2 loads (8 loads in flight) ----
    i32x4 av[4]; f32x4 fv[4]; bool val[4];
#pragma unroll
    for (int sub = 0; sub < 4; ++sub) {
      int j = j0 + cbase + sub * 64;
      bool v = (j < N_NODES);           // j 4-aligned, N%4==0 -> all 4 valid
      int jc = v ? j : (N_NODES - 4);
      av[sub] = *(const i32x4*)(adjrow + jc);
      fv[sub] = *(const f32x4*)(f2 + jc);
      val[sub] = v;
    }
#pragma unroll
    for (int sub = 0; sub < 4; ++sub) {
      float p[4];
#pragma unroll
      for (int e = 0; e < 4; ++e) {
        float ev = f1r + fv[sub][e];
        ev = fmaxf(ev, ALPHA * ev);
        float pv = __expf(ev - Mhat);
        p[e] = (val[sub] && av[sub][e] != 0) ? pv : 0.f;
        sth += p[e];
      }
      uint2 pk;
      pk.x = bf16bits(p[0]) | (bf16bits(p[1]) << 16);
      pk.y = bf16bits(p[2]) | (bf16bits(p[3]) << 16);
      *(uint2*)(ldsB + pboff[sub]) = pk;
    }
    __syncthreads();
    // ---- consumer: A from LDS (swizzled b128), B from global whT ----
#pragma unroll
    for (int ks = 0; ks < 2; ++ks) {
      bf16x8 af = *(const bf16x8*)(ldsB + cboff[ks]);
      const short* bp = bbase + j0 + ks * 32;
#pragma unroll
      for (int cb = 0; cb < 4; ++cb) {
        bf16x8 bf = *(const bf16x8*)(bp + (size_t)cb * 16 * NPAD);
        acc[cb] = __builtin_amdgcn_mfma_f32_16x16x32_bf16(af, bf, acc[cb], 0, 0, 0);
      }
    }
    __syncthreads();
  }

  // ---- denominator: reduce the 16 producer threads of each row ----
  sth += __shfl_xor(sth, 1);
  sth += __shfl_xor(sth, 2);
  sth += __shfl_xor(sth, 4);
  sth += __shfl_xor(sth, 8);
  if ((tid & 15) == 0) sP[split * N_NODES + grow] = sth;

  // ---- cross-wave acc reduce in LDS, non-atomic partial write ----
  float* accS = ldsF;                    // reuse (last loop iter ended in barrier)
#pragma unroll
  for (int cb = 0; cb < 4; ++cb)
#pragma unroll
    for (int q = 0; q < 4; ++q)
      accS[(w * 16 + g * 4 + q) * 64 + cb * 16 + r2] = acc[cb][q];
  __syncthreads();
  int base = split * (N_NODES * D) + rowtile * 1024;
#pragma unroll
  for (int k = 0; k < 4; ++k) {
    int o = tid + k * 256;
    accP[base + o] = accS[o] + accS[1024 + o] + accS[2048 + o] + accS[3072 + o];
  }
}

// ---- k3: out = ELU( (sum of split partials) / s ) ---------------------------
__global__ __launch_bounds__(256) void k3_final(
    const float* __restrict__ accP, const float* __restrict__ sP,
    float* __restrict__ out) {
  int idx = blockIdx.x * 256 + threadIdx.x;
  if (idx >= N_NODES * D) return;
  int row = idx >> 6;
  float sv = (sP[row] + sP[N_NODES + row]) +
             (sP[2 * N_NODES + row] + sP[3 * N_NODES + row]);
  float v = ((accP[idx] + accP[640000 + idx]) +
             (accP[1280000 + idx] + accP[1920000 + idx])) / sv;
  out[idx] = v > 0.f ? v : (__expf(v) - 1.f);
}

extern "C" void kernel_launch(void* const* d_in, const int* in_sizes, int n_in,
                              void* d_out, int out_size, void* d_ws, size_t ws_size,
                              hipStream_t stream) {
  const float* h   = (const float*)d_in[0];
  const int*   adj = (const int*)d_in[1];
  const float* W   = (const float*)d_in[2];
  const float* a   = (const float*)d_in[3];
  float* out = (float*)d_out;

  float* wsf = (float*)d_ws;
  // ws layout (floats):
  // accP [4*640000] | sP [4*10000] | f2max [16] | f1 [10016] | f2 [10016] | whT (bf16 64*10240)
  float* accP   = wsf;
  float* sP     = wsf + 2560000;
  float* f2maxF = wsf + 2600000;
  float* f1W    = wsf + 2600016;
  float* f2W    = wsf + 2610032;
  short* whT    = (short*)(wsf + 2620048);

  hipLaunchKernelGGL(k1_proj, dim3(NPAD / 4), dim3(256), 0, stream,
                     h, W, a, f1W, f2W, whT);
  hipLaunchKernelGGL(k1b_max, dim3(1), dim3(256), 0, stream, f2W, f2maxF);
  hipLaunchKernelGGL(k2_attn, dim3(ROWTILES * NSPLIT), dim3(256), 0, stream,
                     adj, f1W, f2W, f2maxF, whT, accP, sP);
  hipLaunchKernelGGL(k3_final, dim3((N_NODES * D + 255) / 256), dim3(256), 0, stream,
                     accP, sP, out);
}